// Round 1
// baseline (797.176 us; speedup 1.0000x reference)
//
#include <hip/hip_runtime.h>

// SGConv: out = A_norm^2 (x @ W^T) + b, where A_norm = D^-1/2 (A+I) D^-1/2.
// Propagation and the linear layer commute, so we do the 128->64 linear FIRST
// and propagate in 64-dim (lane = feature, wave = node).

#define FIN 128
#define FOUT 64

// ---- CSR build ------------------------------------------------------------

__global__ void count_kernel(const int* __restrict__ ei, int* __restrict__ cnt, int e) {
    int t = blockIdx.x * blockDim.x + threadIdx.x;
    if (t < e) atomicAdd(&cnt[ei[e + t]], 1);   // dst = ei[E + t]
}

__global__ void scan1_kernel(const int* __restrict__ cnt, int* __restrict__ excl,
                             int* __restrict__ bsum, int n) {
    __shared__ int tmp[256];
    int t = threadIdx.x;
    int idx = blockIdx.x * 256 + t;
    int v = (idx < n) ? cnt[idx] : 0;
    tmp[t] = v;
    __syncthreads();
    for (int off = 1; off < 256; off <<= 1) {
        int add = (t >= off) ? tmp[t - off] : 0;
        __syncthreads();
        tmp[t] += add;
        __syncthreads();
    }
    if (idx < n) excl[idx] = tmp[t] - v;      // exclusive within block
    if (t == 255) bsum[blockIdx.x] = tmp[255]; // block total
}

__global__ void scan2_kernel(int* __restrict__ bsum, int nb) {
    __shared__ int tmp[1024];
    int t = threadIdx.x;
    int v = (t < nb) ? bsum[t] : 0;
    tmp[t] = v;
    __syncthreads();
    for (int off = 1; off < 1024; off <<= 1) {
        int add = (t >= off) ? tmp[t - off] : 0;
        __syncthreads();
        tmp[t] += add;
        __syncthreads();
    }
    if (t < nb) bsum[t] = tmp[t] - v;          // exclusive block offsets (in place)
}

__global__ void scan3_kernel(const int* __restrict__ cnt, const int* __restrict__ excl,
                             const int* __restrict__ bsum, int* __restrict__ rowptr,
                             int* __restrict__ cursor, float* __restrict__ dinv,
                             int n, int e) {
    int idx = blockIdx.x * blockDim.x + threadIdx.x;
    if (idx < n) {
        int rp = excl[idx] + bsum[idx >> 8];
        rowptr[idx] = rp;
        cursor[idx] = rp;
        dinv[idx]   = rsqrtf((float)(cnt[idx] + 1));  // +1 self-loop; deg >= 1 always
    }
    if (idx == 0) rowptr[n] = e;
}

__global__ void scatter_kernel(const int* __restrict__ ei, int* __restrict__ cursor,
                               int* __restrict__ col, int e) {
    int t = blockIdx.x * blockDim.x + threadIdx.x;
    if (t < e) {
        int d = ei[e + t];
        int s = ei[t];
        int p = atomicAdd(&cursor[d], 1);
        col[p] = s;
    }
}

// ---- y0 = x @ W^T ---------------------------------------------------------
// Wave per node. Lane o computes output feature o. x row (128 f32) lives as
// float2 per lane, broadcast via __shfl; W packed i-major as float4 in LDS so
// each lane issues ds_read_b128 of 4 consecutive weights.

__global__ void xw_kernel(const float* __restrict__ x, const float* __restrict__ W,
                          float* __restrict__ y, int n) {
    __shared__ float4 Ws4[32 * 64];  // Ws4[j*64+o] = {W[o][4j..4j+3]}, 32 KB
    float* Ws = (float*)Ws4;
    int tid = threadIdx.x;
    for (int idx = tid; idx < FIN * FOUT; idx += blockDim.x) {
        int o = idx >> 7, i = idx & 127;  // coalesced read of W[o][i]
        Ws[((i >> 2) * 64 + o) * 4 + (i & 3)] = W[idx];
    }
    __syncthreads();

    int lane  = tid & 63;
    int wpb   = blockDim.x >> 6;
    int wid   = blockIdx.x * wpb + (tid >> 6);
    int wstep = gridDim.x * wpb;
    for (int nd = wid; nd < n; nd += wstep) {
        float2 xv = ((const float2*)(x + (size_t)nd * FIN))[lane];
        float acc = 0.f;
#pragma unroll
        for (int j = 0; j < 32; ++j) {
            float4 w4 = Ws4[j * 64 + lane];
            float xa = __shfl(xv.x, 2 * j);
            float xb = __shfl(xv.y, 2 * j);
            float xc = __shfl(xv.x, 2 * j + 1);
            float xd = __shfl(xv.y, 2 * j + 1);
            acc += w4.x * xa;
            acc += w4.y * xb;
            acc += w4.z * xc;
            acc += w4.w * xd;
        }
        y[(size_t)nd * FOUT + lane] = acc;
    }
}

// ---- one propagation hop --------------------------------------------------
// Wave per node, lane = feature (FOUT == 64 == wave size).
// acc = dinv[i]^2 * y[i] + sum_{s in in(i)} dinv[s]*dinv[i]*y[s]
// Inner loop unrolled x4 so the 4 col/dinv/row loads overlap (latency hiding).

__global__ void prop_kernel(const float* __restrict__ yin, const int* __restrict__ rowptr,
                            const int* __restrict__ col, const float* __restrict__ dinv,
                            const float* __restrict__ bias, float* __restrict__ yout,
                            int n, int addBias) {
    int wid  = (blockIdx.x * blockDim.x + threadIdx.x) >> 6;
    int lane = threadIdx.x & 63;
    if (wid >= n) return;
    float di  = dinv[wid];
    float acc = di * di * yin[(size_t)wid * FOUT + lane];
    int j = rowptr[wid], end = rowptr[wid + 1];
    for (; j + 3 < end; j += 4) {
        int s0 = col[j], s1 = col[j + 1], s2 = col[j + 2], s3 = col[j + 3];
        float w0 = dinv[s0] * di, w1 = dinv[s1] * di;
        float w2 = dinv[s2] * di, w3 = dinv[s3] * di;
        float v0 = yin[(size_t)s0 * FOUT + lane];
        float v1 = yin[(size_t)s1 * FOUT + lane];
        float v2 = yin[(size_t)s2 * FOUT + lane];
        float v3 = yin[(size_t)s3 * FOUT + lane];
        acc += w0 * v0;
        acc += w1 * v1;
        acc += w2 * v2;
        acc += w3 * v3;
    }
    for (; j < end; ++j) {
        int s = col[j];
        acc += dinv[s] * di * yin[(size_t)s * FOUT + lane];
    }
    if (addBias) acc += bias[lane];
    yout[(size_t)wid * FOUT + lane] = acc;
}

// ---- launch ---------------------------------------------------------------

extern "C" void kernel_launch(void* const* d_in, const int* in_sizes, int n_in,
                              void* d_out, int out_size, void* d_ws, size_t ws_size,
                              hipStream_t stream) {
    const float* x  = (const float*)d_in[0];
    const int*   ei = (const int*)d_in[1];
    const float* W  = (const float*)d_in[2];
    const float* b  = (const float*)d_in[3];
    float* out = (float*)d_out;

    int n = in_sizes[0] / FIN;   // 100000
    int e = in_sizes[1] / 2;     // 1600000
    int NB = (n + 255) / 256;    // 391 (<= 1024 required by scan2)

    // workspace carve (all 4B-aligned; ~33 MB total)
    char* w = (char*)d_ws;
    float* y1     = (float*)w; w += (size_t)n * FOUT * sizeof(float);
    int*   cnt    = (int*)w;   w += (size_t)n * sizeof(int);
    int*   rowptr = (int*)w;   w += (size_t)(n + 1) * sizeof(int);
    int*   cursor = (int*)w;   w += (size_t)n * sizeof(int);
    int*   excl   = (int*)w;   w += (size_t)n * sizeof(int);
    int*   bsum   = (int*)w;   w += (size_t)NB * sizeof(int);
    float* dinv   = (float*)w; w += (size_t)n * sizeof(float);
    int*   col    = (int*)w;   w += (size_t)e * sizeof(int);

    int eb = (e + 255) / 256;

    hipMemsetAsync(cnt, 0, (size_t)n * sizeof(int), stream);
    count_kernel<<<eb, 256, 0, stream>>>(ei, cnt, e);
    scan1_kernel<<<NB, 256, 0, stream>>>(cnt, excl, bsum, n);
    scan2_kernel<<<1, 1024, 0, stream>>>(bsum, NB);
    scan3_kernel<<<NB, 256, 0, stream>>>(cnt, excl, bsum, rowptr, cursor, dinv, n, e);
    scatter_kernel<<<eb, 256, 0, stream>>>(ei, cursor, col, e);

    // y0 = x @ W^T  (written into d_out, which hop1 then consumes)
    xw_kernel<<<2048, 256, 0, stream>>>(x, W, out, n);
    // hop 1: out -> y1
    prop_kernel<<<(n + 3) / 4, 256, 0, stream>>>(out, rowptr, col, dinv, nullptr, y1, n, 0);
    // hop 2: y1 -> out (+bias)
    prop_kernel<<<(n + 3) / 4, 256, 0, stream>>>(y1, rowptr, col, dinv, b, out, n, 1);
}

// Round 2
// 458.193 us; speedup vs baseline: 1.7398x; 1.7398x over previous
//
#include <hip/hip_runtime.h>

// SGConv: out = A_norm^2 (x @ W^T) + b, where A_norm = D^-1/2 (A+I) D^-1/2.
// Linear first (128->64), then 2 propagation hops in 64-dim.

#define FIN 128
#define FOUT 64
#define BN 128   // nodes per block tile in xw
#define KC 64    // k-chunk per staging phase (FIN/KC phases)

// ---- CSR build ------------------------------------------------------------

__global__ void count_kernel(const int* __restrict__ ei, int* __restrict__ cnt, int e) {
    int t = blockIdx.x * blockDim.x + threadIdx.x;
    if (t < e) atomicAdd(&cnt[ei[e + t]], 1);   // dst = ei[E + t]
}

__global__ void scan1_kernel(const int* __restrict__ cnt, int* __restrict__ excl,
                             int* __restrict__ bsum, int n) {
    __shared__ int tmp[256];
    int t = threadIdx.x;
    int idx = blockIdx.x * 256 + t;
    int v = (idx < n) ? cnt[idx] : 0;
    tmp[t] = v;
    __syncthreads();
    for (int off = 1; off < 256; off <<= 1) {
        int add = (t >= off) ? tmp[t - off] : 0;
        __syncthreads();
        tmp[t] += add;
        __syncthreads();
    }
    if (idx < n) excl[idx] = tmp[t] - v;
    if (t == 255) bsum[blockIdx.x] = tmp[255];
}

__global__ void scan2_kernel(int* __restrict__ bsum, int nb) {
    __shared__ int tmp[1024];
    int t = threadIdx.x;
    int v = (t < nb) ? bsum[t] : 0;
    tmp[t] = v;
    __syncthreads();
    for (int off = 1; off < 1024; off <<= 1) {
        int add = (t >= off) ? tmp[t - off] : 0;
        __syncthreads();
        tmp[t] += add;
        __syncthreads();
    }
    if (t < nb) bsum[t] = tmp[t] - v;
}

__global__ void scan3_kernel(const int* __restrict__ cnt, const int* __restrict__ excl,
                             const int* __restrict__ bsum, int* __restrict__ rowptr,
                             int* __restrict__ cursor, float* __restrict__ dinv,
                             int n, int e) {
    int idx = blockIdx.x * blockDim.x + threadIdx.x;
    if (idx < n) {
        int rp = excl[idx] + bsum[idx >> 8];
        rowptr[idx] = rp;
        cursor[idx] = rp;
        dinv[idx]   = rsqrtf((float)(cnt[idx] + 1));
    }
    if (idx == 0) rowptr[n] = e;
}

__global__ void scatter_kernel(const int* __restrict__ ei, int* __restrict__ cursor,
                               int* __restrict__ col, int e) {
    int t = blockIdx.x * blockDim.x + threadIdx.x;
    if (t < e) {
        int d = ei[e + t];
        int s = ei[t];
        int p = atomicAdd(&cursor[d], 1);
        col[p] = s;
    }
}

// ---- y0 = x @ W^T : register-tiled SGEMM ---------------------------------
// Block tile: 128 nodes x 64 outs, 256 threads, 8n x 4o register tile each.
// Both operands staged k-major in LDS, padded so compute ds_read_b128 are
// contiguous (conflict-free) and 16B-aligned. K split into 2 phases of 64
// to keep LDS at 51.2 KB -> 3 blocks/CU.

__global__ __launch_bounds__(256) void xw_kernel(const float* __restrict__ x,
                                                 const float* __restrict__ W,
                                                 float* __restrict__ y, int n) {
    __shared__ float4 xs4[KC][33];   // xs4[k][g] = x[node 4g..4g+3][k]; stride 132 floats
    __shared__ float4 ws4[KC][17];   // ws4[k][g] = W[o 4g..4g+3][k];   stride 68 floats
    float* xsf = (float*)xs4;
    float* wsf = (float*)ws4;

    const int tid   = threadIdx.x;
    const int node0 = blockIdx.x * BN;
    const int n8 = tid >> 4;   // 0..15: node group (8 nodes)
    const int o4 = tid & 15;   // 0..15: out group (4 outs)

    float4 acc[8];
#pragma unroll
    for (int i = 0; i < 8; ++i) acc[i] = make_float4(0.f, 0.f, 0.f, 0.f);

    const int rx = tid >> 4;   // staging row base
    const int cx = tid & 15;   // staging col4

    for (int p = 0; p < FIN / KC; ++p) {
        __syncthreads();
        // stage x tile: 128 rows x KC cols (transpose to k-major)
#pragma unroll
        for (int i = 0; i < 8; ++i) {
            int r  = rx + 16 * i;
            int nd = node0 + r; if (nd > n - 1) nd = n - 1;   // clamp (dup rows harmless)
            float4 v = *(const float4*)(x + (size_t)nd * FIN + p * KC + 4 * cx);
            float* dst = xsf + (4 * cx) * 132 + r;
            dst[0] = v.x; dst[132] = v.y; dst[264] = v.z; dst[396] = v.w;
        }
        // stage W tile: 64 rows x KC cols
#pragma unroll
        for (int i = 0; i < 4; ++i) {
            int o = rx + 16 * i;
            float4 v = *(const float4*)(W + (size_t)o * FIN + p * KC + 4 * cx);
            float* dst = wsf + (4 * cx) * 68 + o;
            dst[0] = v.x; dst[68] = v.y; dst[136] = v.z; dst[204] = v.w;
        }
        __syncthreads();
        // compute: 3 ds_read_b128 + 32 FMA per k
#pragma unroll 4
        for (int k = 0; k < KC; ++k) {
            float4 xa0 = xs4[k][2 * n8];
            float4 xa1 = xs4[k][2 * n8 + 1];
            float4 wb  = ws4[k][o4];
            float xe[8] = {xa0.x, xa0.y, xa0.z, xa0.w, xa1.x, xa1.y, xa1.z, xa1.w};
#pragma unroll
            for (int i = 0; i < 8; ++i) {
                acc[i].x += xe[i] * wb.x;
                acc[i].y += xe[i] * wb.y;
                acc[i].z += xe[i] * wb.z;
                acc[i].w += xe[i] * wb.w;
            }
        }
    }
#pragma unroll
    for (int i = 0; i < 8; ++i) {
        int nd = node0 + 8 * n8 + i;
        if (nd < n) *(float4*)(y + (size_t)nd * FOUT + 4 * o4) = acc[i];
    }
}

// ---- one propagation hop --------------------------------------------------
// Wave per node, lane = feature (FOUT == 64 == wave size).

__global__ void prop_kernel(const float* __restrict__ yin, const int* __restrict__ rowptr,
                            const int* __restrict__ col, const float* __restrict__ dinv,
                            const float* __restrict__ bias, float* __restrict__ yout,
                            int n, int addBias) {
    int wid  = (blockIdx.x * blockDim.x + threadIdx.x) >> 6;
    int lane = threadIdx.x & 63;
    if (wid >= n) return;
    float di  = dinv[wid];
    float acc = di * di * yin[(size_t)wid * FOUT + lane];
    int j = rowptr[wid], end = rowptr[wid + 1];
    for (; j + 3 < end; j += 4) {
        int s0 = col[j], s1 = col[j + 1], s2 = col[j + 2], s3 = col[j + 3];
        float w0 = dinv[s0] * di, w1 = dinv[s1] * di;
        float w2 = dinv[s2] * di, w3 = dinv[s3] * di;
        float v0 = yin[(size_t)s0 * FOUT + lane];
        float v1 = yin[(size_t)s1 * FOUT + lane];
        float v2 = yin[(size_t)s2 * FOUT + lane];
        float v3 = yin[(size_t)s3 * FOUT + lane];
        acc += w0 * v0;
        acc += w1 * v1;
        acc += w2 * v2;
        acc += w3 * v3;
    }
    for (; j < end; ++j) {
        int s = col[j];
        acc += dinv[s] * di * yin[(size_t)s * FOUT + lane];
    }
    if (addBias) acc += bias[lane];
    yout[(size_t)wid * FOUT + lane] = acc;
}

// ---- launch ---------------------------------------------------------------

extern "C" void kernel_launch(void* const* d_in, const int* in_sizes, int n_in,
                              void* d_out, int out_size, void* d_ws, size_t ws_size,
                              hipStream_t stream) {
    const float* x  = (const float*)d_in[0];
    const int*   ei = (const int*)d_in[1];
    const float* W  = (const float*)d_in[2];
    const float* b  = (const float*)d_in[3];
    float* out = (float*)d_out;

    int n = in_sizes[0] / FIN;   // 100000
    int e = in_sizes[1] / 2;     // 1600000
    int NB = (n + 255) / 256;    // 391 (<= 1024 required by scan2)

    char* w = (char*)d_ws;
    float* y1     = (float*)w; w += (size_t)n * FOUT * sizeof(float);
    int*   cnt    = (int*)w;   w += (size_t)n * sizeof(int);
    int*   rowptr = (int*)w;   w += (size_t)(n + 1) * sizeof(int);
    int*   cursor = (int*)w;   w += (size_t)n * sizeof(int);
    int*   excl   = (int*)w;   w += (size_t)n * sizeof(int);
    int*   bsum   = (int*)w;   w += (size_t)NB * sizeof(int);
    float* dinv   = (float*)w; w += (size_t)n * sizeof(float);
    int*   col    = (int*)w;   w += (size_t)e * sizeof(int);

    int eb = (e + 255) / 256;

    hipMemsetAsync(cnt, 0, (size_t)n * sizeof(int), stream);
    count_kernel<<<eb, 256, 0, stream>>>(ei, cnt, e);
    scan1_kernel<<<NB, 256, 0, stream>>>(cnt, excl, bsum, n);
    scan2_kernel<<<1, 1024, 0, stream>>>(bsum, NB);
    scan3_kernel<<<NB, 256, 0, stream>>>(cnt, excl, bsum, rowptr, cursor, dinv, n, e);
    scatter_kernel<<<eb, 256, 0, stream>>>(ei, cursor, col, e);

    xw_kernel<<<(n + BN - 1) / BN, 256, 0, stream>>>(x, W, out, n);
    prop_kernel<<<(n + 3) / 4, 256, 0, stream>>>(out, rowptr, col, dinv, nullptr, y1, n, 0);
    prop_kernel<<<(n + 3) / 4, 256, 0, stream>>>(y1, rowptr, col, dinv, b, out, n, 1);
}

// Round 3
// 392.095 us; speedup vs baseline: 2.0331x; 1.1686x over previous
//
#include <hip/hip_runtime.h>

// SGConv: out = A_norm^2 (x @ W^T) + b, where A_norm = D^-1/2 (A+I) D^-1/2.
// Linear first (128->64), then 2 propagation hops in 64-dim.

#define FIN 128
#define FOUT 64
#define BN 128   // nodes per block tile in xw
#define KC 64    // k-chunk per staging phase (FIN/KC phases)

// ---- CSR build ------------------------------------------------------------
// Pass 1 claims each edge's slot within its dst bucket (rank) while counting.
// Pass 2 (after scan) computes the final position with NO atomics and writes
// col with a nontemporal store (random 4B writes: avoid full-line writebacks
// -- R2 profile showed 102 MB WRITE_SIZE = 1.6M x 64B lines from scatter).

__global__ void count_rank_kernel(const int* __restrict__ ei, int* __restrict__ cnt,
                                  int* __restrict__ rank, int e) {
    int t = blockIdx.x * blockDim.x + threadIdx.x;
    if (t < e) rank[t] = atomicAdd(&cnt[ei[e + t]], 1);   // dst = ei[E + t]
}

__global__ void scan1_kernel(const int* __restrict__ cnt, int* __restrict__ excl,
                             int* __restrict__ bsum, int n) {
    __shared__ int tmp[256];
    int t = threadIdx.x;
    int idx = blockIdx.x * 256 + t;
    int v = (idx < n) ? cnt[idx] : 0;
    tmp[t] = v;
    __syncthreads();
    for (int off = 1; off < 256; off <<= 1) {
        int add = (t >= off) ? tmp[t - off] : 0;
        __syncthreads();
        tmp[t] += add;
        __syncthreads();
    }
    if (idx < n) excl[idx] = tmp[t] - v;
    if (t == 255) bsum[blockIdx.x] = tmp[255];
}

__global__ void scan2_kernel(int* __restrict__ bsum, int nb) {
    __shared__ int tmp[1024];
    int t = threadIdx.x;
    int v = (t < nb) ? bsum[t] : 0;
    tmp[t] = v;
    __syncthreads();
    for (int off = 1; off < 1024; off <<= 1) {
        int add = (t >= off) ? tmp[t - off] : 0;
        __syncthreads();
        tmp[t] += add;
        __syncthreads();
    }
    if (t < nb) bsum[t] = tmp[t] - v;
}

__global__ void scan3_kernel(const int* __restrict__ cnt, const int* __restrict__ excl,
                             const int* __restrict__ bsum, int* __restrict__ rowptr,
                             float* __restrict__ dinv, int n, int e) {
    int idx = blockIdx.x * blockDim.x + threadIdx.x;
    if (idx < n) {
        rowptr[idx] = excl[idx] + bsum[idx >> 8];
        dinv[idx]   = rsqrtf((float)(cnt[idx] + 1));
    }
    if (idx == 0) rowptr[n] = e;
}

__global__ void scatter_kernel(const int* __restrict__ ei, const int* __restrict__ rowptr,
                               const int* __restrict__ rank, int* __restrict__ col, int e) {
    int t = blockIdx.x * blockDim.x + threadIdx.x;
    if (t < e) {
        int d = ei[e + t];
        int p = rowptr[d] + rank[t];
        __builtin_nontemporal_store(ei[t], &col[p]);
    }
}

// ---- y0 = x @ W^T : register-tiled SGEMM ---------------------------------

__global__ __launch_bounds__(256) void xw_kernel(const float* __restrict__ x,
                                                 const float* __restrict__ W,
                                                 float* __restrict__ y, int n) {
    __shared__ float4 xs4[KC][33];   // xs4[k][g] = x[node 4g..4g+3][k]; stride 132 floats
    __shared__ float4 ws4[KC][17];   // ws4[k][g] = W[o 4g..4g+3][k];   stride 68 floats
    float* xsf = (float*)xs4;
    float* wsf = (float*)ws4;

    const int tid   = threadIdx.x;
    const int node0 = blockIdx.x * BN;
    const int n8 = tid >> 4;
    const int o4 = tid & 15;

    float4 acc[8];
#pragma unroll
    for (int i = 0; i < 8; ++i) acc[i] = make_float4(0.f, 0.f, 0.f, 0.f);

    const int rx = tid >> 4;
    const int cx = tid & 15;

    for (int p = 0; p < FIN / KC; ++p) {
        __syncthreads();
#pragma unroll
        for (int i = 0; i < 8; ++i) {
            int r  = rx + 16 * i;
            int nd = node0 + r; if (nd > n - 1) nd = n - 1;
            float4 v = *(const float4*)(x + (size_t)nd * FIN + p * KC + 4 * cx);
            float* dst = xsf + (4 * cx) * 132 + r;
            dst[0] = v.x; dst[132] = v.y; dst[264] = v.z; dst[396] = v.w;
        }
#pragma unroll
        for (int i = 0; i < 4; ++i) {
            int o = rx + 16 * i;
            float4 v = *(const float4*)(W + (size_t)o * FIN + p * KC + 4 * cx);
            float* dst = wsf + (4 * cx) * 68 + o;
            dst[0] = v.x; dst[68] = v.y; dst[136] = v.z; dst[204] = v.w;
        }
        __syncthreads();
#pragma unroll 4
        for (int k = 0; k < KC; ++k) {
            float4 xa0 = xs4[k][2 * n8];
            float4 xa1 = xs4[k][2 * n8 + 1];
            float4 wb  = ws4[k][o4];
            float xe[8] = {xa0.x, xa0.y, xa0.z, xa0.w, xa1.x, xa1.y, xa1.z, xa1.w};
#pragma unroll
            for (int i = 0; i < 8; ++i) {
                acc[i].x += xe[i] * wb.x;
                acc[i].y += xe[i] * wb.y;
                acc[i].z += xe[i] * wb.z;
                acc[i].w += xe[i] * wb.w;
            }
        }
    }
#pragma unroll
    for (int i = 0; i < 8; ++i) {
        int nd = node0 + 8 * n8 + i;
        if (nd < n) *(float4*)(y + (size_t)nd * FOUT + 4 * o4) = acc[i];
    }
}

// ---- one propagation hop --------------------------------------------------
// Wave per node, lane = feature (FOUT == 64 == wave size).

__global__ void prop_kernel(const float* __restrict__ yin, const int* __restrict__ rowptr,
                            const int* __restrict__ col, const float* __restrict__ dinv,
                            const float* __restrict__ bias, float* __restrict__ yout,
                            int n, int addBias) {
    int wid  = (blockIdx.x * blockDim.x + threadIdx.x) >> 6;
    int lane = threadIdx.x & 63;
    if (wid >= n) return;
    float di  = dinv[wid];
    float acc = di * di * yin[(size_t)wid * FOUT + lane];
    int j = rowptr[wid], end = rowptr[wid + 1];
    for (; j + 3 < end; j += 4) {
        int s0 = col[j], s1 = col[j + 1], s2 = col[j + 2], s3 = col[j + 3];
        float w0 = dinv[s0] * di, w1 = dinv[s1] * di;
        float w2 = dinv[s2] * di, w3 = dinv[s3] * di;
        float v0 = yin[(size_t)s0 * FOUT + lane];
        float v1 = yin[(size_t)s1 * FOUT + lane];
        float v2 = yin[(size_t)s2 * FOUT + lane];
        float v3 = yin[(size_t)s3 * FOUT + lane];
        acc += w0 * v0;
        acc += w1 * v1;
        acc += w2 * v2;
        acc += w3 * v3;
    }
    for (; j < end; ++j) {
        int s = col[j];
        acc += dinv[s] * di * yin[(size_t)s * FOUT + lane];
    }
    if (addBias) acc += bias[lane];
    yout[(size_t)wid * FOUT + lane] = acc;
}

// ---- launch ---------------------------------------------------------------

extern "C" void kernel_launch(void* const* d_in, const int* in_sizes, int n_in,
                              void* d_out, int out_size, void* d_ws, size_t ws_size,
                              hipStream_t stream) {
    const float* x  = (const float*)d_in[0];
    const int*   ei = (const int*)d_in[1];
    const float* W  = (const float*)d_in[2];
    const float* b  = (const float*)d_in[3];
    float* out = (float*)d_out;

    int n = in_sizes[0] / FIN;   // 100000
    int e = in_sizes[1] / 2;     // 1600000
    int NB = (n + 255) / 256;    // 391 (<= 1024 required by scan2)

    char* w = (char*)d_ws;
    float* y1     = (float*)w; w += (size_t)n * FOUT * sizeof(float);
    int*   cnt    = (int*)w;   w += (size_t)n * sizeof(int);
    int*   rowptr = (int*)w;   w += (size_t)(n + 1) * sizeof(int);
    int*   excl   = (int*)w;   w += (size_t)n * sizeof(int);
    int*   bsum   = (int*)w;   w += (size_t)NB * sizeof(int);
    float* dinv   = (float*)w; w += (size_t)n * sizeof(float);
    int*   col    = (int*)w;   w += (size_t)e * sizeof(int);
    int*   rank   = (int*)w;   w += (size_t)e * sizeof(int);

    int eb = (e + 255) / 256;

    hipMemsetAsync(cnt, 0, (size_t)n * sizeof(int), stream);
    count_rank_kernel<<<eb, 256, 0, stream>>>(ei, cnt, rank, e);
    scan1_kernel<<<NB, 256, 0, stream>>>(cnt, excl, bsum, n);
    scan2_kernel<<<1, 1024, 0, stream>>>(bsum, NB);
    scan3_kernel<<<NB, 256, 0, stream>>>(cnt, excl, bsum, rowptr, dinv, n, e);
    scatter_kernel<<<eb, 256, 0, stream>>>(ei, rowptr, rank, col, e);

    xw_kernel<<<(n + BN - 1) / BN, 256, 0, stream>>>(x, W, out, n);
    prop_kernel<<<(n + 3) / 4, 256, 0, stream>>>(out, rowptr, col, dinv, nullptr, y1, n, 0);
    prop_kernel<<<(n + 3) / 4, 256, 0, stream>>>(y1, rowptr, col, dinv, b, out, n, 1);
}